// Round 7
// baseline (586.446 us; speedup 1.0000x reference)
//
#include <hip/hip_runtime.h>
#include <hip/hip_bf16.h>
#include <math.h>

typedef __bf16 bf16x8 __attribute__((ext_vector_type(8)));
typedef short  s16x8  __attribute__((ext_vector_type(8)));
typedef short  s16x4  __attribute__((ext_vector_type(4)));
typedef float  f32x16 __attribute__((ext_vector_type(16)));
typedef unsigned short u16;

// ---- sizes ----
#define NN 32
#define CC 256
#define HH 56
#define WW 56
#define HP 68            // padded spatial (6 halo each side)
#define XP2_BYTES 75759616ull            // 32*68*68*256*2
#define XP2_OFF 0ull
#define WT3_OFF 75759616ull              // 100*32768 B = 3276800
#define T1_OFF  79036416ull              // 32*256*56*4 = 1835008
#define T9_OFF  80871424ull              // 32*56*56*4

__device__ inline u16 f2bf(float f) {
    unsigned int u = __builtin_bit_cast(unsigned int, f);
    u = (u + 0x7fffu + ((u >> 16) & 1u)) >> 16;   // RNE
    return (u16)u;
}

__device__ inline void gl_lds16(const char* g, char* l) {
    __builtin_amdgcn_global_load_lds(
        (const __attribute__((address_space(1))) unsigned int*)g,
        (__attribute__((address_space(3))) unsigned int*)l, 16, 0, 0);
}

// ---- zero only the halo of xp2 (interior fully written by prep) ----
__global__ void zero_halo(u16* __restrict__ xp2) {
    const int total = NN * 1488 * 32;           // 16B chunks
    int i = blockIdx.x * blockDim.x + threadIdx.x;
    const int stride = gridDim.x * blockDim.x;
    uint4 z; z.x = z.y = z.z = z.w = 0u;
    for (; i < total; i += stride) {
        int chunk = i & 31;
        int pid = i >> 5;
        int n = pid / 1488;
        int hp = pid - n * 1488;
        int row, col;
        if (hp < 816) { int r = hp / 68; col = hp - r * 68; row = (r < 6) ? r : r + 56; }
        else { int hq = hp - 816; int rr = hq / 12; int c12 = hq - rr * 12;
               row = 6 + rr; col = (c12 < 6) ? c12 : c12 + 56; }
        *(uint4*)((char*)xp2 + ((((size_t)n * HP + row) * HP + col) * 512) + chunk * 16) = z;
    }
}

// ---- pack w7 -> wt3 in 8-phase K-tile order ----
// per ktile (64 K-elems = kn pair) block of 32KB: [mi(4)][ks(4)][wr(2)][lane(64)][8 u16]
// c_out = wr*128 + mi*32 + (lane&31); k64 = ks*16 + (lane>>5)*8 + j.
__global__ __launch_bounds__(256)
void pack_w(const float* __restrict__ w7, u16* __restrict__ wt3) {
    int idx = blockIdx.x * 256 + threadIdx.x;    // 256*6400 total
    int c_out = idx / 6400;
    int k = idx - c_out * 6400;
    int cin = k / 25;
    int tap = k - cin * 25;
    int ktile = tap * 4 + (cin >> 6);
    int k64 = cin & 63;
    int ks = k64 >> 4, lhi = (k64 >> 3) & 1, j = k64 & 7;
    int lane = lhi * 32 + (c_out & 31);
    int mi = (c_out >> 5) & 3, wr = c_out >> 7;
    wt3[(size_t)ktile * 16384 + mi * 4096 + ks * 1024 + wr * 512 + lane * 8 + j] = f2bf(w7[idx]);
}

// ---- fused prep: t1 (row max) + t9 (softmax of einsum) + pack x ----
// (r6 winner, unchanged)
__global__ __launch_bounds__(256)
void prep(const float* __restrict__ x, const float* __restrict__ w6,
          float* __restrict__ t1, float* __restrict__ t9,
          u16* __restrict__ xp2) {
    const int n = blockIdx.x / HH;
    const int h = blockIdx.x % HH;
    const int tid = threadIdx.x;
    const int lane = tid & 63;
    const int wid = tid >> 6;
    const int g16 = lane >> 4;        // 0..3: c-subrow within wave
    const int wq  = lane & 15;        // w-quad, active if <14
    const bool act = wq < 14;
    __shared__ u16 xbuf[64 * 60];
    __shared__ float sacc[16][56];
    const float* xrow = x + ((size_t)(n * CC) * HH + h) * WW;
    u16* dst = xp2 + (((size_t)n * HP + h + 6) * HP + 6) * CC;
    float a0 = 0.f, a1 = 0.f, a2 = 0.f, a3 = 0.f;
    for (int g = 0; g < 4; ++g) {
        if (g) __syncthreads();
#pragma unroll
        for (int it = 0; it < 4; ++it) {
            const int cl = wid * 16 + it * 4 + g16;
            const int c  = g * 64 + cl;
            float4 v = make_float4(0.f, 0.f, 0.f, 0.f);
            if (act) v = *(const float4*)(xrow + (size_t)c * (HH * WW) + wq * 4);
            if (act) {
                s16x4 pk;
                pk[0] = (short)f2bf(v.x); pk[1] = (short)f2bf(v.y);
                pk[2] = (short)f2bf(v.z); pk[3] = (short)f2bf(v.w);
                *(s16x4*)(xbuf + cl * 60 + wq * 4) = pk;
            }
            float m = act ? fmaxf(fmaxf(v.x, v.y), fmaxf(v.z, v.w)) : -INFINITY;
#pragma unroll
            for (int off = 8; off > 0; off >>= 1)
                m = fmaxf(m, __shfl_xor(m, off));
            if (wq == 0) t1[(size_t)(n * CC + c) * HH + h] = m;
            if (act) {
                const float wc = w6[c];
                a0 += wc * (1.f - 2.f * __builtin_amdgcn_rcpf(__expf(2.f * fmaxf(v.x, 0.f)) + 1.f));
                a1 += wc * (1.f - 2.f * __builtin_amdgcn_rcpf(__expf(2.f * fmaxf(v.y, 0.f)) + 1.f));
                a2 += wc * (1.f - 2.f * __builtin_amdgcn_rcpf(__expf(2.f * fmaxf(v.z, 0.f)) + 1.f));
                a3 += wc * (1.f - 2.f * __builtin_amdgcn_rcpf(__expf(2.f * fmaxf(v.w, 0.f)) + 1.f));
            }
        }
        __syncthreads();
        for (int id = tid; id < WW * 8; id += 256) {
            int p = id >> 3, ch8 = id & 7;
            s16x8 pk;
#pragma unroll
            for (int j = 0; j < 8; ++j)
                pk[j] = (short)xbuf[(ch8 * 8 + j) * 60 + p];
            *(s16x8*)(dst + (size_t)p * CC + g * 64 + ch8 * 8) = pk;
        }
    }
    if (act) {
        float* sl = sacc[wid * 4 + g16];
        sl[wq * 4 + 0] = a0; sl[wq * 4 + 1] = a1;
        sl[wq * 4 + 2] = a2; sl[wq * 4 + 3] = a3;
    }
    __syncthreads();
    if (wid == 0) {
        const bool valid = lane < WW;
        float s = 0.f;
        if (valid) {
#pragma unroll
            for (int gi = 0; gi < 16; ++gi) s += sacc[gi][lane];
        }
        float sm = valid ? s : -INFINITY;
        float mx = sm;
#pragma unroll
        for (int off = 32; off > 0; off >>= 1)
            mx = fmaxf(mx, __shfl_xor(mx, off));
        float e = valid ? expf(s - mx) : 0.f;
        float tot = e;
#pragma unroll
        for (int off = 32; off > 0; off >>= 1)
            tot += __shfl_xor(tot, off);
        if (valid) t9[((size_t)n * HH + h) * WW + lane] = e / tot;
    }
}

// ---- main: 8-phase implicit GEMM, 256 couts x 256 pos, BK=64, dbuf=2 ----
// 512 thr = 8 waves (2M x 4N), wave 128x64, 32x32x16 MFMA, fragment-order LDS
// (all frag reads = wave-contiguous 1KB, conflict-free). 100 K-tiles; per tile
// 4 phases split by mi-quadrant: p0 {vmcnt(6) gate; bar; read bv(8)+av(mi0);
// stage straggler(t+1); MFMA mi0; bar} then p1..p3 {read av(mi_p); stage
// A(t+2,mi_{p-1}) B(t+2,ks_{p-1}); bar; MFMA mi_p; bar}. Region ledger:
// stages only ever target regions whose reads completed a phase earlier
// (MFMA's lgkm dependency forces read-completion before each end-barrier).
// 2 gl_lds/thread/phase -> counted vmcnt(6) once per tile = 3 half-tiles in
// flight (T3+T4); setprio around MFMA clusters (T5).
__global__ __launch_bounds__(512, 2)
void conv_main(const char* __restrict__ xp2b, const char* __restrict__ wt3b,
               const float* __restrict__ x, const float* __restrict__ t1,
               const float* __restrict__ t9, float* __restrict__ out) {
    extern __shared__ __align__(16) char smem[];   // 2 bufs x 64KB = 128 KiB
    const int bid = blockIdx.x;
    const int tile = (bid & 7) * 49 + (bid >> 3);   // XCD-aware swizzle
    const int tid  = threadIdx.x;
    const int wid  = tid >> 6;
    const int lane = tid & 63;
    const int l31 = lane & 31;
    const int lhi = lane >> 5;
    const int wr = wid >> 2;          // cout half: rows [wr*128, +128)
    const int wc = wid & 3;           // pos quarter: cols [wc*64, +64)

    // B gather: wave wid stages pos-block cb=wid (32 positions).
    unsigned vb;
    {
        int p = tile * 256 + wid * 32 + l31;
        int n = p / (HH * WW);
        int rem = p - n * (HH * WW);
        int hh = rem / WW;
        int ww = rem - hh * WW;
        vb = ((((unsigned)n * HP + hh + 6) * HP) + ww + 6) * 512 + lhi * 16;
    }
    const unsigned aS = (wid & 3) * 2048 + (wid >> 2) * 1024 + lane * 16;

    // stage one 8KB A-quadrant (mi) / one 8KB B-slab (ks) of K-tile t2.
    // t2 may exceed 99 (tail dummies wrap; those buffers are never read).
    auto stageA = [&](int t2, int mi) {
        const int kt = (t2 < 100) ? t2 : (t2 - 100);
        char* d = smem + (size_t)(t2 & 1) * 65536 + mi * 8192 + aS;
        const char* g = wt3b + (size_t)kt * 32768 + mi * 8192 + aS;
        gl_lds16(g, d);
    };
    auto stageB = [&](int t2, int ks) {
        const int kt = (t2 < 100) ? t2 : (t2 - 100);
        const int tap = kt >> 2, u = kt & 3;
        const char* gb = xp2b +
            (ptrdiff_t)((tap / 5) * 3 - 6) * (HP * 512) +
            (ptrdiff_t)((tap % 5) * 3 - 6) * 512 + u * 128 + ks * 32 + vb;
        char* d = smem + (size_t)(t2 & 1) * 65536 + 32768 + ks * 8192 + wid * 1024 + lane * 16;
        gl_lds16(gb, d);
    };

    f32x16 acc[4][2];
#pragma unroll
    for (int mi = 0; mi < 4; ++mi)
#pragma unroll
        for (int nb = 0; nb < 2; ++nb)
#pragma unroll
            for (int r = 0; r < 16; ++r)
                acc[mi][nb][r] = 0.f;

    // frag read offsets (wave-contiguous 1KB -> conflict-free)
    const int aoff = wr * 1024 + lane * 16;              // + mi*8192 + ks*2048
    const int boff = 32768 + wc * 2048 + lane * 16;      // + ks*8192 + nb*1024

    // prologue: tile0 fully (8 quanta), tile1 partial (6); gate covers tile0.
    stageA(0, 0); stageA(0, 1); stageA(0, 2); stageA(0, 3);
    stageB(0, 0); stageB(0, 1); stageB(0, 2); stageB(0, 3);
    stageA(1, 0); stageA(1, 1); stageA(1, 2);
    stageB(1, 0); stageB(1, 1); stageB(1, 2);

#define PHASE_N(MI)                                                            \
    {                                                                          \
        _Pragma("unroll")                                                      \
        for (int ks = 0; ks < 4; ++ks)                                         \
            av[ks] = *(const bf16x8*)(const void*)(bp + aoff + MI * 8192 + ks * 2048); \
        stageA(t + 2, MI - 1); stageB(t + 2, MI - 1);                          \
        __builtin_amdgcn_s_barrier();                                          \
        __builtin_amdgcn_sched_barrier(0);                                     \
        __builtin_amdgcn_s_setprio(1);                                         \
        _Pragma("unroll")                                                      \
        for (int ks = 0; ks < 4; ++ks) {                                       \
            acc[MI][0] = __builtin_amdgcn_mfma_f32_32x32x16_bf16(              \
                av[ks], bv[0][ks], acc[MI][0], 0, 0, 0);                       \
            acc[MI][1] = __builtin_amdgcn_mfma_f32_32x32x16_bf16(              \
                av[ks], bv[1][ks], acc[MI][1], 0, 0, 0);                       \
        }                                                                      \
        __builtin_amdgcn_s_setprio(0);                                         \
        __builtin_amdgcn_s_barrier();                                          \
        __builtin_amdgcn_sched_barrier(0);                                     \
    }

    for (int t = 0; t < 100; ++t) {
        const char* bp = smem + (size_t)(t & 1) * 65536;
        bf16x8 av[4], bv[2][4];
        // ---- phase 0: tile gate + all B frags + A(mi0) + straggler stage ----
        asm volatile("s_waitcnt vmcnt(6)" ::: "memory");
        __builtin_amdgcn_s_barrier();
        __builtin_amdgcn_sched_barrier(0);
#pragma unroll
        for (int ks = 0; ks < 4; ++ks) {
            bv[0][ks] = *(const bf16x8*)(const void*)(bp + boff + ks * 8192);
            bv[1][ks] = *(const bf16x8*)(const void*)(bp + boff + ks * 8192 + 1024);
            av[ks]    = *(const bf16x8*)(const void*)(bp + aoff + ks * 2048);
        }
        stageA(t + 1, 3); stageB(t + 1, 3);
        __builtin_amdgcn_s_setprio(1);
#pragma unroll
        for (int ks = 0; ks < 4; ++ks) {
            acc[0][0] = __builtin_amdgcn_mfma_f32_32x32x16_bf16(
                av[ks], bv[0][ks], acc[0][0], 0, 0, 0);
            acc[0][1] = __builtin_amdgcn_mfma_f32_32x32x16_bf16(
                av[ks], bv[1][ks], acc[0][1], 0, 0, 0);
        }
        __builtin_amdgcn_s_setprio(0);
        __builtin_amdgcn_s_barrier();
        __builtin_amdgcn_sched_barrier(0);
        // ---- phases 1-3 ----
        PHASE_N(1)
        PHASE_N(2)
        PHASE_N(3)
    }
#undef PHASE_N
    // drain: in-flight DMA must not outlive this block's LDS
    asm volatile("s_waitcnt vmcnt(0)" ::: "memory");

    // epilogue: out = t1 - (t9 * roll(x,2,h) + x * t7)
    // C/D map (m74/m101): col = lane&31, row = (r&3) + 8*(r>>2) + 4*(lane>>5)
#pragma unroll
    for (int nb = 0; nb < 2; ++nb) {
        const int p = tile * 256 + wc * 64 + nb * 32 + l31;
        const int n = p / (HH * WW);
        const int rem = p - n * (HH * WW);
        const int h = rem / WW;
        const int w = rem - h * WW;
        const float t9v = t9[((size_t)n * HH + h) * WW + w];
        const int hprev = (h >= 2) ? (h - 2) : (h + HH - 2);
#pragma unroll
        for (int mi = 0; mi < 4; ++mi) {
            const int c0 = wr * 128 + mi * 32 + 4 * lhi;
#pragma unroll
            for (int r = 0; r < 16; ++r) {
                const int c = c0 + (r & 3) + 8 * (r >> 2);
                const size_t rowi = (size_t)(n * CC + c) * HH;
                const float t1v = t1[rowi + h];
                const float xv = x[(rowi + h) * WW + w];
                const float xr = x[(rowi + hprev) * WW + w];
                out[(rowi + h) * WW + w] = t1v - (t9v * xr + xv * acc[mi][nb][r]);
            }
        }
    }
}

extern "C" void kernel_launch(void* const* d_in, const int* in_sizes, int n_in,
                              void* d_out, int out_size, void* d_ws, size_t ws_size,
                              hipStream_t stream) {
    const float* x  = (const float*)d_in[0];
    const float* w6 = (const float*)d_in[1];
    const float* w7 = (const float*)d_in[2];
    float* out = (float*)d_out;
    char* ws = (char*)d_ws;
    u16*   xp2 = (u16*)(ws + XP2_OFF);
    u16*   wt3 = (u16*)(ws + WT3_OFF);
    float* t1  = (float*)(ws + T1_OFF);
    float* t9  = (float*)(ws + T9_OFF);

    static bool lds_cfg_done = false;
    if (!lds_cfg_done) {
        (void)hipFuncSetAttribute((const void*)conv_main,
                                  hipFuncAttributeMaxDynamicSharedMemorySize,
                                  131072);
        lds_cfg_done = true;
    }

    zero_halo<<<dim3(1024), dim3(256), 0, stream>>>(xp2);
    pack_w<<<dim3(6400), dim3(256), 0, stream>>>(w7, wt3);
    prep<<<dim3(NN * HH), dim3(256), 0, stream>>>(x, w6, t1, t9, xp2);
    conv_main<<<dim3(392), dim3(512), 131072, stream>>>((const char*)xp2, (const char*)wt3,
                                                        x, t1, t9, out);
}